// Round 14
// baseline (118.439 us; speedup 1.0000x reference)
//
#include <hip/hip_runtime.h>
#include <hip/hip_bf16.h>
#include <math.h>

// QANet Context-Query attention. B=32 H=128 C=2048 Q=256.
// R13: micro-bundle on R12's structure:
//   (1) Ssoft: double-buffered Bs (1 barrier/K-step instead of 2),
//   (2) out_mfma: register prefetch of next-step qB/Tb fragments,
//   (3) Tred: vectorized u32x2 loads (4 j per thread).
// Structure: direct-ctx Ssoft, Eb=exp(S), exp-free colZ, bf16 Tpart,
// rowinv epilogue.

constexpr int kB = 32, kH = 128, kC = 2048, kQ = 256;
constexpr int kColChunks = 128;          // (kC/64) blocks * 4 waves
constexpr float kNEG = -1e30f;

typedef short bf16x8 __attribute__((ext_vector_type(8)));
typedef float f32x4 __attribute__((ext_vector_type(4)));

static __device__ __forceinline__ unsigned short f2bf(float f) {
    __hip_bfloat16 h = __float2bfloat16(f);
    return __builtin_bit_cast(unsigned short, h);
}
static __device__ __forceinline__ float bf2f(unsigned short u) {
    unsigned int x = ((unsigned int)u) << 16;
    return __builtin_bit_cast(float, x);
}

// One q read -> qT[b,j,h]=bf16(q), qB[b,h,j]=bf16(q), part_q.
__global__ __launch_bounds__(256) void k_prep_q(const float* __restrict__ q,
                                                const float* __restrict__ w_q,
                                                unsigned short* __restrict__ qT,
                                                unsigned short* __restrict__ qB,
                                                float* __restrict__ part_q) {
    int j0 = blockIdx.x * 64, b = blockIdx.y;
    __shared__ unsigned short tile[64 * 136];
    __shared__ float pcp[4][64];
    int t = threadIdx.x;
    int jl = t & 63, hg = t >> 6, hb = hg * 2;
    float accq = 0.f;
#pragma unroll
    for (int r = 0; r < 16; ++r) {
        int h = r * 8 + hb;
        float v0 = q[((size_t)b * kH + h) * kQ + j0 + jl];
        float v1 = q[((size_t)b * kH + h + 1) * kQ + j0 + jl];
        accq += v0 * w_q[h] + v1 * w_q[h + 1];
        qB[((size_t)b * kH + h) * kQ + j0 + jl]     = f2bf(v0);
        qB[((size_t)b * kH + h + 1) * kQ + j0 + jl] = f2bf(v1);
        unsigned int pk = (unsigned int)f2bf(v0) | ((unsigned int)f2bf(v1) << 16);
        *(unsigned int*)&tile[jl * 136 + h] = pk;
    }
    pcp[hg][jl] = accq;
    __syncthreads();
    if (t < 64) part_q[b * kQ + j0 + t] = pcp[0][t] + pcp[1][t] + pcp[2][t] + pcp[3][t];
#pragma unroll
    for (int r = 0; r < 4; ++r) {
        int idx = r * 256 + t;
        int j = idx >> 4, hc = (idx & 15) * 8;
        *(bf16x8*)&qT[((size_t)b * kQ + j0 + j) * kH + hc] =
            *(const bf16x8*)&tile[j * 136 + hc];
    }
}

// Fused S + softmax. Block = 64 i x 256 j; wave = 16 i x 256 j.
// A-fragments direct from global ctx (w_cq folded); part_c from same loads.
// Bs double-buffered: one barrier per K-step.
__global__ __launch_bounds__(256) void k_Ssoft(const float* __restrict__ ctx,
                                               const unsigned short* __restrict__ qT,
                                               const float* __restrict__ w_c,
                                               const float* __restrict__ w_cq,
                                               const float* __restrict__ part_q,
                                               const float* __restrict__ bias,
                                               const int* __restrict__ qmask,
                                               const int* __restrict__ cmask,
                                               unsigned short* __restrict__ Eb,
                                               float* __restrict__ rowinv,
                                               float* __restrict__ ps) {
    int i0 = blockIdx.x * 64, b = blockIdx.y;
    __shared__ unsigned short Bs[2][256 * 40];
    __shared__ float smpq[256];
    __shared__ int smqm[256];
    __shared__ float smwc[128];
    __shared__ float smwq[128];
    __shared__ float smpc[64];
    int t = threadIdx.x;
    int lane = t & 63, w = t >> 6;
    int lrow = lane & 15, q4 = lane >> 4, kgrp = q4 * 8;
    smpq[t] = part_q[b * kQ + t];
    smqm[t] = qmask[b * kQ + t];
    if (t < 128) smwc[t] = w_c[t];
    else smwq[t - 128] = w_cq[t - 128];

    int jB = t >> 2, hcB = (t & 3) * 8;   // staging map: 4 thr/row, 8 h each
#pragma unroll
    for (int r2 = 0; r2 < 4; ++r2) {
        int jj = (r2 * 256 + t) >> 2, hh = ((r2 * 256 + t) & 3) * 8;
        *(bf16x8*)&Bs[0][jj * 40 + hh] =
            *(const bf16x8*)&qT[((size_t)b * kQ + jj) * kH + hh];
    }
    __syncthreads();

    const float* cbase = ctx + (size_t)b * kH * kC + i0 + w * 16 + lrow;
    float pcl = 0.f;

    f32x4 acc[16];
#pragma unroll
    for (int nt = 0; nt < 16; ++nt) acc[nt] = (f32x4){0.f, 0.f, 0.f, 0.f};

#pragma unroll
    for (int kk = 0; kk < 4; ++kk) {
        int h0 = kk * 32;
        int cur = kk & 1;
        bf16x8 af;
#pragma unroll
        for (int e = 0; e < 8; ++e) {
            int h = h0 + kgrp + e;
            float v = cbase[(size_t)h * kC];
            pcl += v * smwc[h];
            af[e] = (short)f2bf(v * smwq[h]);
        }
        if (kk < 3) {   // stage next K-step into the other buffer
            int h1 = h0 + 32;
#pragma unroll
            for (int r2 = 0; r2 < 4; ++r2) {
                int jj = (r2 * 256 + t) >> 2, hh = ((r2 * 256 + t) & 3) * 8;
                *(bf16x8*)&Bs[cur ^ 1][jj * 40 + hh] =
                    *(const bf16x8*)&qT[((size_t)b * kQ + jj) * kH + h1 + hh];
            }
        }
#pragma unroll
        for (int nt = 0; nt < 16; ++nt) {
            bf16x8 bf = *(const bf16x8*)&Bs[cur][(nt * 16 + lrow) * 40 + kgrp];
            acc[nt] = __builtin_amdgcn_mfma_f32_16x16x32_bf16(af, bf, acc[nt], 0, 0, 0);
        }
        __syncthreads();
    }

    pcl += __shfl_xor(pcl, 16);
    pcl += __shfl_xor(pcl, 32);
    if (q4 == 0) smpc[w * 16 + lrow] = pcl;
    __syncthreads();

    float bs = bias[0];
    float pq[16];
    int qm[16];
#pragma unroll
    for (int nt = 0; nt < 16; ++nt) {
        int col = nt * 16 + lrow;
        pq[nt] = smpq[col];
        qm[nt] = smqm[col];
    }
    int rowbase = i0 + w * 16 + q4 * 4;
    float pc[4];
    int cmr[4];
#pragma unroll
    for (int r = 0; r < 4; ++r) {
        pc[r] = smpc[w * 16 + q4 * 4 + r] + bs;
        cmr[r] = cmask[b * kC + rowbase + r];
    }
#pragma unroll
    for (int nt = 0; nt < 16; ++nt)
#pragma unroll
        for (int r = 0; r < 4; ++r)
            acc[nt][r] += pc[r] + pq[nt];

    float cs[16];
#pragma unroll
    for (int nt = 0; nt < 16; ++nt) cs[nt] = 0.f;

#pragma unroll
    for (int r = 0; r < 4; ++r) {
        float rmax = kNEG;
#pragma unroll
        for (int nt = 0; nt < 16; ++nt)
            if (qm[nt]) rmax = fmaxf(rmax, acc[nt][r]);
        rmax = fmaxf(rmax, __shfl_xor(rmax, 1));
        rmax = fmaxf(rmax, __shfl_xor(rmax, 2));
        rmax = fmaxf(rmax, __shfl_xor(rmax, 4));
        rmax = fmaxf(rmax, __shfl_xor(rmax, 8));
        float e[16];
        float rsum = 0.f;
#pragma unroll
        for (int nt = 0; nt < 16; ++nt) {
            e[nt] = qm[nt] ? __expf(acc[nt][r] - rmax) : 0.f;
            rsum += e[nt];
        }
        rsum += __shfl_xor(rsum, 1);
        rsum += __shfl_xor(rsum, 2);
        rsum += __shfl_xor(rsum, 4);
        rsum += __shfl_xor(rsum, 8);
        float emax = __expf(rmax);
        float Z = rsum * emax;
        unsigned short* dst = Eb + ((size_t)b * kC + rowbase + r) * kQ;
#pragma unroll
        for (int nt = 0; nt < 16; ++nt)
            dst[nt * 16 + lrow] = f2bf(e[nt] * emax);
        if (lrow == 0)
            rowinv[b * kC + rowbase + r] = Z > 0.f ? 1.f / Z : 0.f;
        if (cmr[r]) {
#pragma unroll
            for (int nt = 0; nt < 16; ++nt)
                cs[nt] += e[nt] * emax;
        }
    }
#pragma unroll
    for (int nt = 0; nt < 16; ++nt) {
        cs[nt] += __shfl_xor(cs[nt], 16);
        cs[nt] += __shfl_xor(cs[nt], 32);
    }
    int chunk = blockIdx.x * 4 + w;
#pragma unroll
    for (int k = 0; k < 4; ++k) {
        int nt = q4 * 4 + k;
        int col = nt * 16 + lrow;
        ps[((size_t)b * kColChunks + chunk) * kQ + col] = cs[nt];
    }
}

// colinv = 1/colZ (0 if colZ==0: fully-masked column, harmless downstream).
__global__ __launch_bounds__(256) void k_colZ(const float* __restrict__ ps,
                                              float* __restrict__ colinv) {
    int id = blockIdx.x * 256 + threadIdx.x;   // over B*Q
    int b = id / kQ, j = id % kQ;
    float s = 0.f;
#pragma unroll 8
    for (int c = 0; c < kColChunks; ++c)
        s += ps[((size_t)b * kColChunks + c) * kQ + j];
    colinv[id] = s > 0.f ? 1.f / s : 0.f;
}

// T partials via MFMA. One 512-thr block per (chunk, b): 128 h x 256 j.
// Et staging: u32-pair Eb loads + in-register 2x2 transpose, pitch 42.
__global__ __launch_bounds__(512) void k_T2_mfma(const unsigned short* __restrict__ Eb,
                                                 const float* __restrict__ ctx,
                                                 const int* __restrict__ cmask,
                                                 unsigned short* __restrict__ Tpart) {
    int chunk = blockIdx.x, b = blockIdx.y;
    __shared__ unsigned short Et[256 * 42];   // [j][i] transposed E tile, pitch 42
    __shared__ unsigned short Bs[128 * 40];   // [h][i] ctx bf16
    __shared__ int smc[256];
    int t = threadIdx.x;
    if (t < 256) smc[t] = cmask[b * kC + chunk * 256 + t];
    int lane = t & 63, wave = t >> 6;
    int wm = wave >> 1, wn = wave & 1;
    int lrow = lane & 15, kgrp = (lane >> 4) * 8;
    int ip = t >> 5, js2 = t & 31;            // ip: i-pair [0,16); js2: j-pair [0,32)
    int hB = t >> 2, isegB = (t & 3) * 8;

    f32x4 acc[2][8];
#pragma unroll
    for (int mt = 0; mt < 2; ++mt)
#pragma unroll
        for (int nt = 0; nt < 8; ++nt)
            acc[mt][nt] = (f32x4){0.f, 0.f, 0.f, 0.f};
    __syncthreads();

    for (int kk = 0; kk < 8; ++kk) {
        int i0 = chunk * 256 + kk * 32;
        int li = kk * 32 + 2 * ip;
        unsigned int m0 = smc[li]     ? 0xFFFFFFFFu : 0u;
        unsigned int m1 = smc[li + 1] ? 0xFFFFFFFFu : 0u;
        const unsigned short* r0 = Eb + ((size_t)b * kC + i0 + 2 * ip) * kQ;
#pragma unroll
        for (int m = 0; m < 4; ++m) {
            int j = 2 * js2 + 64 * m;
            unsigned int a  = *(const unsigned int*)&r0[j] & m0;
            unsigned int bv = *(const unsigned int*)&r0[kQ + j] & m1;
            unsigned int lo = (a & 0xFFFFu) | (bv << 16);
            unsigned int hi = (a >> 16) | (bv & 0xFFFF0000u);
            *(unsigned int*)&Et[(size_t)j * 42 + 2 * ip]       = lo;
            *(unsigned int*)&Et[(size_t)(j + 1) * 42 + 2 * ip] = hi;
        }
        {   // A: ctx fp32 -> bf16, row hB, 8-i segment
            const float* cb = ctx + ((size_t)b * kH + hB) * kC + i0 + isegB;
            float4 a0 = *(const float4*)cb;
            float4 a1 = *(const float4*)(cb + 4);
            float vv[8] = {a0.x, a0.y, a0.z, a0.w, a1.x, a1.y, a1.z, a1.w};
            bf16x8 p0;
#pragma unroll
            for (int e = 0; e < 8; ++e) p0[e] = (short)f2bf(vv[e]);
            *(bf16x8*)&Bs[hB * 40 + isegB] = p0;
        }
        __syncthreads();
        bf16x8 af[2], bfr[8];
#pragma unroll
        for (int mt = 0; mt < 2; ++mt)
            af[mt] = *(const bf16x8*)&Bs[(wm * 32 + mt * 16 + lrow) * 40 + kgrp];
#pragma unroll
        for (int nt = 0; nt < 8; ++nt)
            bfr[nt] = *(const bf16x8*)&Et[(size_t)(wn * 128 + nt * 16 + lrow) * 42 + kgrp];
#pragma unroll
        for (int nt = 0; nt < 8; ++nt)
#pragma unroll
            for (int mt = 0; mt < 2; ++mt)
                acc[mt][nt] = __builtin_amdgcn_mfma_f32_16x16x32_bf16(af[mt], bfr[nt], acc[mt][nt], 0, 0, 0);
        __syncthreads();
    }

    const size_t M = (size_t)kB * kH * kQ;
#pragma unroll
    for (int mt = 0; mt < 2; ++mt)
#pragma unroll
        for (int r = 0; r < 4; ++r) {
            int h = wm * 32 + mt * 16 + (lane >> 4) * 4 + r;
            unsigned short* dst = Tpart + (size_t)chunk * M + ((size_t)b * kH + h) * kQ + wn * 128 + lrow;
#pragma unroll
            for (int nt = 0; nt < 8; ++nt)
                dst[nt * 16] = f2bf(acc[mt][nt][r]);
        }
}

// T_bf16 = colinv * sum_chunk Tpart. Vectorized: 4 j per thread, u32x2 loads.
__global__ __launch_bounds__(256) void k_Tred(const unsigned short* __restrict__ Tpart,
                                              const float* __restrict__ colinv,
                                              unsigned short* __restrict__ Tb) {
    size_t id4 = ((size_t)blockIdx.x * 256 + threadIdx.x) * 4;   // over B*H*Q
    const size_t M = (size_t)kB * kH * kQ;
    int j = (int)(id4 & (kQ - 1));
    int b = (int)(id4 / ((size_t)kH * kQ));
    float s0 = 0.f, s1 = 0.f, s2 = 0.f, s3 = 0.f;
#pragma unroll
    for (int c = 0; c < 8; ++c) {
        uint2 v = *(const uint2*)&Tpart[c * M + id4];
        s0 += bf2f((unsigned short)(v.x & 0xFFFFu));
        s1 += bf2f((unsigned short)(v.x >> 16));
        s2 += bf2f((unsigned short)(v.y & 0xFFFFu));
        s3 += bf2f((unsigned short)(v.y >> 16));
    }
    const float* ci = colinv + b * kQ + j;
    uint2 o;
    o.x = (unsigned int)f2bf(s0 * ci[0]) | ((unsigned int)f2bf(s1 * ci[1]) << 16);
    o.y = (unsigned int)f2bf(s2 * ci[2]) | ((unsigned int)f2bf(s3 * ci[3]) << 16);
    *(uint2*)&Tb[id4] = o;
}

// Output kernel: 64 i x 128 h per block. A = Eb via LDS; B fragments (qB/Tb)
// direct from global with next-step register prefetch. Epilogue: x rowinv,
// one ctx read, 4 outputs.
__global__ __launch_bounds__(256) void k_out_mfma(const unsigned short* __restrict__ Eb,
                                                  const unsigned short* __restrict__ qB,
                                                  const unsigned short* __restrict__ Tb,
                                                  const float* __restrict__ ctx,
                                                  const float* __restrict__ rowinv,
                                                  float* __restrict__ out) {
    int i0 = blockIdx.x * 64;
    int b  = blockIdx.y;
    __shared__ unsigned short As[64 * 40];
    __shared__ float stgC[64 * 68];
    __shared__ float stgT[64 * 68];
    int t = threadIdx.x;
    int rA = t >> 2, cA = (t & 3) * 8;
    int lane = t & 63, wave = t >> 6;
    int hw = wave * 32;
    int kgrp = (lane >> 4) * 8;
    int lrow = lane & 15, q4 = lane >> 4;

    f32x4 accC[4][2];
    f32x4 accT[4][2];
#pragma unroll
    for (int mt = 0; mt < 4; ++mt)
#pragma unroll
        for (int nt = 0; nt < 2; ++nt) {
            accC[mt][nt] = (f32x4){0.f, 0.f, 0.f, 0.f};
            accT[mt][nt] = (f32x4){0.f, 0.f, 0.f, 0.f};
        }

    // prefetch kk=0 B fragments
    bf16x8 bqn[2], btn[2];
#pragma unroll
    for (int nt = 0; nt < 2; ++nt) {
        int h = hw + nt * 16 + lrow;
        bqn[nt] = *(const bf16x8*)&qB[((size_t)b * kH + h) * kQ + kgrp];
        btn[nt] = *(const bf16x8*)&Tb[((size_t)b * kH + h) * kQ + kgrp];
    }

    for (int kk = 0; kk < 8; ++kk) {
        int j0 = kk * 32;
        bf16x8 bqc[2] = {bqn[0], bqn[1]};
        bf16x8 btc[2] = {btn[0], btn[1]};
        if (kk < 7) {
            int j1 = j0 + 32;
#pragma unroll
            for (int nt = 0; nt < 2; ++nt) {
                int h = hw + nt * 16 + lrow;
                bqn[nt] = *(const bf16x8*)&qB[((size_t)b * kH + h) * kQ + j1 + kgrp];
                btn[nt] = *(const bf16x8*)&Tb[((size_t)b * kH + h) * kQ + j1 + kgrp];
            }
        }
        *(bf16x8*)&As[rA * 40 + cA] =
            *(const bf16x8*)&Eb[((size_t)b * kC + i0 + rA) * kQ + j0 + cA];
        __syncthreads();
        bf16x8 af[4];
#pragma unroll
        for (int mt = 0; mt < 4; ++mt)
            af[mt] = *(const bf16x8*)&As[(mt * 16 + lrow) * 40 + kgrp];
#pragma unroll
        for (int nt = 0; nt < 2; ++nt) {
#pragma unroll
            for (int mt = 0; mt < 4; ++mt) {
                accC[mt][nt] = __builtin_amdgcn_mfma_f32_16x16x32_bf16(af[mt], bqc[nt], accC[mt][nt], 0, 0, 0);
                accT[mt][nt] = __builtin_amdgcn_mfma_f32_16x16x32_bf16(af[mt], btc[nt], accT[mt][nt], 0, 0, 0);
            }
        }
        __syncthreads();
    }

    const size_t N = (size_t)kB * kH * kC;
    int ii = t & 63, hb = t >> 6;
    float riv = rowinv[b * kC + i0 + ii];
#pragma unroll
    for (int g = 0; g < 2; ++g) {
        if ((wave >> 1) == g) {
            int hloc = (wave & 1) * 32;
#pragma unroll
            for (int mt = 0; mt < 4; ++mt)
#pragma unroll
                for (int nt = 0; nt < 2; ++nt)
#pragma unroll
                    for (int r = 0; r < 4; ++r) {
                        int rowh = hloc + nt * 16 + lrow;
                        int coli = mt * 16 + q4 * 4 + r;
                        stgC[rowh * 68 + coli] = accC[mt][nt][r];
                        stgT[rowh * 68 + coli] = accT[mt][nt][r];
                    }
        }
        __syncthreads();
#pragma unroll 4
        for (int p = 0; p < 16; ++p) {
            int hl = hb + p * 4;
            int h = g * 64 + hl;
            float vc = stgC[hl * 68 + ii] * riv;
            float vt = stgT[hl * 68 + ii] * riv;
            size_t base = ((size_t)b * kH + h) * kC + i0 + ii;
            float c = ctx[base];
            out[base]         = c;
            out[N + base]     = vc;
            out[2 * N + base] = c * vc;
            out[3 * N + base] = c * vt;
        }
        __syncthreads();
    }
}

extern "C" void kernel_launch(void* const* d_in, const int* in_sizes, int n_in,
                              void* d_out, int out_size, void* d_ws, size_t ws_size,
                              hipStream_t stream) {
    const float* ctx   = (const float*)d_in[0];
    const float* q     = (const float*)d_in[1];
    const int*   cmask = (const int*)d_in[2];
    const int*   qmask = (const int*)d_in[3];
    const float* w_c   = (const float*)d_in[4];
    const float* w_q   = (const float*)d_in[5];
    const float* w_cq  = (const float*)d_in[6];
    const float* bias  = (const float*)d_in[7];
    float* out = (float*)d_out;

    // Workspace (~42 MB of 512 MiB).
    unsigned short* Eb = (unsigned short*)d_ws;                   // B*C*Q bf16
    unsigned short* qB = Eb + (size_t)kB * kC * kQ;               // B*H*Q bf16
    unsigned short* Tb = qB + (size_t)kB * kH * kQ;               // B*H*Q bf16
    float* part_q = (float*)(Tb + (size_t)kB * kH * kQ);          // B*Q
    float* rowinv = part_q + kB * kQ;                             // B*C
    float* colinv = rowinv + kB * kC;                             // B*Q
    float* ps     = colinv + kB * kQ;                             // B*128*Q
    size_t need = (size_t)((char*)(ps + (size_t)kB * kColChunks * kQ) - (char*)d_ws);
    if (ws_size < need) return;

    // d_out scratch (consumed before k_out_mfma writes):
    //   [0 ..)             : Tpart (8 * B*H*Q bf16 = 16.8 MB)
    //   [2N, ..) floats    : qT (B*Q*H bf16)
    const size_t N = (size_t)kB * kH * kC;
    unsigned short* Tpart = (unsigned short*)out;
    unsigned short* qT    = (unsigned short*)(out + 2 * N);

    k_prep_q<<<dim3(kQ / 64, kB), 256, 0, stream>>>(q, w_q, qT, qB, part_q);
    k_Ssoft<<<dim3(kC / 64, kB), 256, 0, stream>>>(ctx, qT, w_c, w_cq, part_q, bias,
                                                   qmask, cmask, Eb, rowinv, ps);
    k_colZ<<<kB * kQ / 256, 256, 0, stream>>>(ps, colinv);
    k_T2_mfma<<<dim3(8, kB), 512, 0, stream>>>(Eb, ctx, cmask, Tpart);
    k_Tred<<<kB * kH * kQ / 1024, 256, 0, stream>>>(Tpart, colinv, Tb);
    k_out_mfma<<<dim3(kC / 64, kB), 256, 0, stream>>>(Eb, qB, Tb, ctx, rowinv, out);
}

// Round 15
// 110.848 us; speedup vs baseline: 1.0685x; 1.0685x over previous
//
#include <hip/hip_runtime.h>
#include <hip/hip_bf16.h>
#include <math.h>

// QANet Context-Query attention. B=32 H=128 C=2048 Q=256.
// R14 = R10 verbatim (session best: 110.8us). R11/R13 micro-opt attempts both
// regressed (occupancy/redundant-read costs); R12 confirmed the plateau.
// Structure: direct-ctx Ssoft (w_cq folded, part_c from same loads),
// Eb=bf16(exp(S)), exp-free colZ, single-pass T2 (ctx+Eb read once),
// bf16 Tpart, rowinv in out-epilogue.

constexpr int kB = 32, kH = 128, kC = 2048, kQ = 256;
constexpr int kColChunks = 128;          // (kC/64) blocks * 4 waves
constexpr float kNEG = -1e30f;

typedef short bf16x8 __attribute__((ext_vector_type(8)));
typedef float f32x4 __attribute__((ext_vector_type(4)));

static __device__ __forceinline__ unsigned short f2bf(float f) {
    __hip_bfloat16 h = __float2bfloat16(f);
    return __builtin_bit_cast(unsigned short, h);
}
static __device__ __forceinline__ float bf2f(unsigned short u) {
    unsigned int x = ((unsigned int)u) << 16;
    return __builtin_bit_cast(float, x);
}

// One q read -> qT[b,j,h]=bf16(q), qB[b,h,j]=bf16(q), part_q.
__global__ __launch_bounds__(256) void k_prep_q(const float* __restrict__ q,
                                                const float* __restrict__ w_q,
                                                unsigned short* __restrict__ qT,
                                                unsigned short* __restrict__ qB,
                                                float* __restrict__ part_q) {
    int j0 = blockIdx.x * 64, b = blockIdx.y;
    __shared__ unsigned short tile[64 * 136];
    __shared__ float pcp[4][64];
    int t = threadIdx.x;
    int jl = t & 63, hg = t >> 6, hb = hg * 2;
    float accq = 0.f;
#pragma unroll
    for (int r = 0; r < 16; ++r) {
        int h = r * 8 + hb;
        float v0 = q[((size_t)b * kH + h) * kQ + j0 + jl];
        float v1 = q[((size_t)b * kH + h + 1) * kQ + j0 + jl];
        accq += v0 * w_q[h] + v1 * w_q[h + 1];
        qB[((size_t)b * kH + h) * kQ + j0 + jl]     = f2bf(v0);
        qB[((size_t)b * kH + h + 1) * kQ + j0 + jl] = f2bf(v1);
        unsigned int pk = (unsigned int)f2bf(v0) | ((unsigned int)f2bf(v1) << 16);
        *(unsigned int*)&tile[jl * 136 + h] = pk;
    }
    pcp[hg][jl] = accq;
    __syncthreads();
    if (t < 64) part_q[b * kQ + j0 + t] = pcp[0][t] + pcp[1][t] + pcp[2][t] + pcp[3][t];
#pragma unroll
    for (int r = 0; r < 4; ++r) {
        int idx = r * 256 + t;
        int j = idx >> 4, hc = (idx & 15) * 8;
        *(bf16x8*)&qT[((size_t)b * kQ + j0 + j) * kH + hc] =
            *(const bf16x8*)&tile[j * 136 + hc];
    }
}

// Fused S + softmax. Block = 64 i x 256 j; wave = 16 i x 256 j.
// A-fragments direct from global ctx (w_cq folded); part_c from same loads.
// Writes Eb = bf16(exp(S)) (qmasked), rowinv = 1/rowZ, col partial sums.
__global__ __launch_bounds__(256) void k_Ssoft(const float* __restrict__ ctx,
                                               const unsigned short* __restrict__ qT,
                                               const float* __restrict__ w_c,
                                               const float* __restrict__ w_cq,
                                               const float* __restrict__ part_q,
                                               const float* __restrict__ bias,
                                               const int* __restrict__ qmask,
                                               const int* __restrict__ cmask,
                                               unsigned short* __restrict__ Eb,
                                               float* __restrict__ rowinv,
                                               float* __restrict__ ps) {
    int i0 = blockIdx.x * 64, b = blockIdx.y;
    __shared__ unsigned short Bs[256 * 40];
    __shared__ float smpq[256];
    __shared__ int smqm[256];
    __shared__ float smwc[128];
    __shared__ float smwq[128];
    __shared__ float smpc[64];
    int t = threadIdx.x;
    int lane = t & 63, w = t >> 6;
    int lrow = lane & 15, q4 = lane >> 4, kgrp = q4 * 8;
    smpq[t] = part_q[b * kQ + t];
    smqm[t] = qmask[b * kQ + t];
    if (t < 128) smwc[t] = w_c[t];
    else smwq[t - 128] = w_cq[t - 128];
    __syncthreads();

    const float* cbase = ctx + (size_t)b * kH * kC + i0 + w * 16 + lrow;
    float pcl = 0.f;

    f32x4 acc[16];
#pragma unroll
    for (int nt = 0; nt < 16; ++nt) acc[nt] = (f32x4){0.f, 0.f, 0.f, 0.f};

#pragma unroll
    for (int kk = 0; kk < 4; ++kk) {
        int h0 = kk * 32;
        bf16x8 af;
#pragma unroll
        for (int e = 0; e < 8; ++e) {
            int h = h0 + kgrp + e;
            float v = cbase[(size_t)h * kC];
            pcl += v * smwc[h];
            af[e] = (short)f2bf(v * smwq[h]);
        }
#pragma unroll
        for (int r2 = 0; r2 < 4; ++r2) {
            int idx = r2 * 256 + t;
            int jB = idx >> 2, hcB = (idx & 3) * 8;
            *(bf16x8*)&Bs[jB * 40 + hcB] =
                *(const bf16x8*)&qT[((size_t)b * kQ + jB) * kH + h0 + hcB];
        }
        __syncthreads();
#pragma unroll
        for (int nt = 0; nt < 16; ++nt) {
            bf16x8 bf = *(const bf16x8*)&Bs[(nt * 16 + lrow) * 40 + kgrp];
            acc[nt] = __builtin_amdgcn_mfma_f32_16x16x32_bf16(af, bf, acc[nt], 0, 0, 0);
        }
        __syncthreads();
    }

    pcl += __shfl_xor(pcl, 16);
    pcl += __shfl_xor(pcl, 32);
    if (q4 == 0) smpc[w * 16 + lrow] = pcl;
    __syncthreads();

    float bs = bias[0];
    float pq[16];
    int qm[16];
#pragma unroll
    for (int nt = 0; nt < 16; ++nt) {
        int col = nt * 16 + lrow;
        pq[nt] = smpq[col];
        qm[nt] = smqm[col];
    }
    int rowbase = i0 + w * 16 + q4 * 4;
    float pc[4];
    int cmr[4];
#pragma unroll
    for (int r = 0; r < 4; ++r) {
        pc[r] = smpc[w * 16 + q4 * 4 + r] + bs;
        cmr[r] = cmask[b * kC + rowbase + r];
    }
#pragma unroll
    for (int nt = 0; nt < 16; ++nt)
#pragma unroll
        for (int r = 0; r < 4; ++r)
            acc[nt][r] += pc[r] + pq[nt];

    float cs[16];
#pragma unroll
    for (int nt = 0; nt < 16; ++nt) cs[nt] = 0.f;

#pragma unroll
    for (int r = 0; r < 4; ++r) {
        float rmax = kNEG;
#pragma unroll
        for (int nt = 0; nt < 16; ++nt)
            if (qm[nt]) rmax = fmaxf(rmax, acc[nt][r]);
        rmax = fmaxf(rmax, __shfl_xor(rmax, 1));
        rmax = fmaxf(rmax, __shfl_xor(rmax, 2));
        rmax = fmaxf(rmax, __shfl_xor(rmax, 4));
        rmax = fmaxf(rmax, __shfl_xor(rmax, 8));
        float e[16];
        float rsum = 0.f;
#pragma unroll
        for (int nt = 0; nt < 16; ++nt) {
            e[nt] = qm[nt] ? __expf(acc[nt][r] - rmax) : 0.f;
            rsum += e[nt];
        }
        rsum += __shfl_xor(rsum, 1);
        rsum += __shfl_xor(rsum, 2);
        rsum += __shfl_xor(rsum, 4);
        rsum += __shfl_xor(rsum, 8);
        float emax = __expf(rmax);
        float Z = rsum * emax;
        unsigned short* dst = Eb + ((size_t)b * kC + rowbase + r) * kQ;
#pragma unroll
        for (int nt = 0; nt < 16; ++nt)
            dst[nt * 16 + lrow] = f2bf(e[nt] * emax);
        if (lrow == 0)
            rowinv[b * kC + rowbase + r] = Z > 0.f ? 1.f / Z : 0.f;
        if (cmr[r]) {
#pragma unroll
            for (int nt = 0; nt < 16; ++nt)
                cs[nt] += e[nt] * emax;
        }
    }
#pragma unroll
    for (int nt = 0; nt < 16; ++nt) {
        cs[nt] += __shfl_xor(cs[nt], 16);
        cs[nt] += __shfl_xor(cs[nt], 32);
    }
    int chunk = blockIdx.x * 4 + w;
#pragma unroll
    for (int k = 0; k < 4; ++k) {
        int nt = q4 * 4 + k;
        int col = nt * 16 + lrow;
        ps[((size_t)b * kColChunks + chunk) * kQ + col] = cs[nt];
    }
}

// colinv = 1/colZ (0 if colZ==0: fully-masked column, harmless downstream).
__global__ __launch_bounds__(256) void k_colZ(const float* __restrict__ ps,
                                              float* __restrict__ colinv) {
    int id = blockIdx.x * 256 + threadIdx.x;   // over B*Q
    int b = id / kQ, j = id % kQ;
    float s = 0.f;
#pragma unroll 8
    for (int c = 0; c < kColChunks; ++c)
        s += ps[((size_t)b * kColChunks + c) * kQ + j];
    colinv[id] = s > 0.f ? 1.f / s : 0.f;
}

// T partials via MFMA. One 512-thr block per (chunk, b): 128 h x 256 j.
// Each ctx/Eb element read exactly once. 8 waves: wm=wave>>1 (32-h quarter),
// wn=wave&1 (128-j half); acc 2x8 f32x4. Tpart stored bf16.
__global__ __launch_bounds__(512) void k_T2_mfma(const unsigned short* __restrict__ Eb,
                                                 const float* __restrict__ ctx,
                                                 const int* __restrict__ cmask,
                                                 unsigned short* __restrict__ Tpart) {
    int chunk = blockIdx.x, b = blockIdx.y;
    __shared__ unsigned short Et[256 * 40];   // [j][i] transposed E tile
    __shared__ unsigned short Bs[128 * 40];   // [h][i] ctx bf16
    __shared__ int smc[256];
    int t = threadIdx.x;
    if (t < 256) smc[t] = cmask[b * kC + chunk * 256 + t];
    int lane = t & 63, wave = t >> 6;
    int wm = wave >> 1, wn = wave & 1;
    int lrow = lane & 15, kgrp = (lane >> 4) * 8;
    int ip = t >> 5, js = t & 31;
    int hB = t >> 2, isegB = (t & 3) * 8;

    f32x4 acc[2][8];
#pragma unroll
    for (int mt = 0; mt < 2; ++mt)
#pragma unroll
        for (int nt = 0; nt < 8; ++nt)
            acc[mt][nt] = (f32x4){0.f, 0.f, 0.f, 0.f};
    __syncthreads();

    for (int kk = 0; kk < 8; ++kk) {
        int i0 = chunk * 256 + kk * 32;
        int li = kk * 32 + 2 * ip;
        unsigned int m0 = smc[li]     ? 0xFFFFu : 0u;
        unsigned int m1 = smc[li + 1] ? 0xFFFFu : 0u;
        const unsigned short* r0 = Eb + ((size_t)b * kC + i0 + 2 * ip) * kQ;
#pragma unroll
        for (int m = 0; m < 8; ++m) {
            int j = js + 32 * m;
            unsigned int e0 = (unsigned int)r0[j] & m0;
            unsigned int e1 = (unsigned int)r0[kQ + j] & m1;
            *(unsigned int*)&Et[j * 40 + 2 * ip] = e0 | (e1 << 16);
        }
        {   // A: ctx fp32 -> bf16, row hB, 8-i segment
            const float* cb = ctx + ((size_t)b * kH + hB) * kC + i0 + isegB;
            float4 a0 = *(const float4*)cb;
            float4 a1 = *(const float4*)(cb + 4);
            float vv[8] = {a0.x, a0.y, a0.z, a0.w, a1.x, a1.y, a1.z, a1.w};
            bf16x8 p0;
#pragma unroll
            for (int e = 0; e < 8; ++e) p0[e] = (short)f2bf(vv[e]);
            *(bf16x8*)&Bs[hB * 40 + isegB] = p0;
        }
        __syncthreads();
        bf16x8 af[2], bfr[8];
#pragma unroll
        for (int mt = 0; mt < 2; ++mt)
            af[mt] = *(const bf16x8*)&Bs[(wm * 32 + mt * 16 + lrow) * 40 + kgrp];
#pragma unroll
        for (int nt = 0; nt < 8; ++nt)
            bfr[nt] = *(const bf16x8*)&Et[(wn * 128 + nt * 16 + lrow) * 40 + kgrp];
#pragma unroll
        for (int nt = 0; nt < 8; ++nt)
#pragma unroll
            for (int mt = 0; mt < 2; ++mt)
                acc[mt][nt] = __builtin_amdgcn_mfma_f32_16x16x32_bf16(af[mt], bfr[nt], acc[mt][nt], 0, 0, 0);
        __syncthreads();
    }

    const size_t M = (size_t)kB * kH * kQ;
#pragma unroll
    for (int mt = 0; mt < 2; ++mt)
#pragma unroll
        for (int r = 0; r < 4; ++r) {
            int h = wm * 32 + mt * 16 + (lane >> 4) * 4 + r;
            unsigned short* dst = Tpart + (size_t)chunk * M + ((size_t)b * kH + h) * kQ + wn * 128 + lrow;
#pragma unroll
            for (int nt = 0; nt < 8; ++nt)
                dst[nt * 16] = f2bf(acc[mt][nt][r]);
        }
}

// T_bf16[b,h,j] = bf16( colinv[b,j] * sum_chunk bf2f(Tpart[chunk][b,h,j]) )
__global__ __launch_bounds__(256) void k_Tred(const unsigned short* __restrict__ Tpart,
                                              const float* __restrict__ colinv,
                                              unsigned short* __restrict__ Tb) {
    size_t id = (size_t)blockIdx.x * 256 + threadIdx.x;   // over B*H*Q
    const size_t M = (size_t)kB * kH * kQ;
    int j = (int)(id % kQ);
    int b = (int)(id / ((size_t)kH * kQ));
    float s = 0.f;
#pragma unroll
    for (int c = 0; c < 8; ++c) s += bf2f(Tpart[c * M + id]);
    Tb[id] = f2bf(s * colinv[b * kQ + j]);
}

// Output kernel: 64 i x 128 h per block. A = Eb via LDS (each elem read once
// per block); B fragments (qB/Tb) direct from global (L2-hot). Epilogue:
// x rowinv, one ctx read, 4 outputs.
__global__ __launch_bounds__(256) void k_out_mfma(const unsigned short* __restrict__ Eb,
                                                  const unsigned short* __restrict__ qB,
                                                  const unsigned short* __restrict__ Tb,
                                                  const float* __restrict__ ctx,
                                                  const float* __restrict__ rowinv,
                                                  float* __restrict__ out) {
    int i0 = blockIdx.x * 64;
    int b  = blockIdx.y;
    __shared__ unsigned short As[64 * 40];
    __shared__ float stgC[64 * 68];
    __shared__ float stgT[64 * 68];
    int t = threadIdx.x;
    int rA = t >> 2, cA = (t & 3) * 8;
    int lane = t & 63, wave = t >> 6;
    int hw = wave * 32;
    int kgrp = (lane >> 4) * 8;
    int lrow = lane & 15, q4 = lane >> 4;

    f32x4 accC[4][2];
    f32x4 accT[4][2];
#pragma unroll
    for (int mt = 0; mt < 4; ++mt)
#pragma unroll
        for (int nt = 0; nt < 2; ++nt) {
            accC[mt][nt] = (f32x4){0.f, 0.f, 0.f, 0.f};
            accT[mt][nt] = (f32x4){0.f, 0.f, 0.f, 0.f};
        }

    for (int kk = 0; kk < 8; ++kk) {
        int j0 = kk * 32;
        *(bf16x8*)&As[rA * 40 + cA] =
            *(const bf16x8*)&Eb[((size_t)b * kC + i0 + rA) * kQ + j0 + cA];
        __syncthreads();
        bf16x8 af[4];
#pragma unroll
        for (int mt = 0; mt < 4; ++mt)
            af[mt] = *(const bf16x8*)&As[(mt * 16 + lrow) * 40 + kgrp];
#pragma unroll
        for (int nt = 0; nt < 2; ++nt) {
            int h = hw + nt * 16 + lrow;
            bf16x8 bq = *(const bf16x8*)&qB[((size_t)b * kH + h) * kQ + j0 + kgrp];
            bf16x8 bt = *(const bf16x8*)&Tb[((size_t)b * kH + h) * kQ + j0 + kgrp];
#pragma unroll
            for (int mt = 0; mt < 4; ++mt) {
                accC[mt][nt] = __builtin_amdgcn_mfma_f32_16x16x32_bf16(af[mt], bq, accC[mt][nt], 0, 0, 0);
                accT[mt][nt] = __builtin_amdgcn_mfma_f32_16x16x32_bf16(af[mt], bt, accT[mt][nt], 0, 0, 0);
            }
        }
        __syncthreads();
    }

    const size_t N = (size_t)kB * kH * kC;
    int ii = t & 63, hb = t >> 6;
    float riv = rowinv[b * kC + i0 + ii];
#pragma unroll
    for (int g = 0; g < 2; ++g) {
        if ((wave >> 1) == g) {
            int hloc = (wave & 1) * 32;
#pragma unroll
            for (int mt = 0; mt < 4; ++mt)
#pragma unroll
                for (int nt = 0; nt < 2; ++nt)
#pragma unroll
                    for (int r = 0; r < 4; ++r) {
                        int rowh = hloc + nt * 16 + lrow;
                        int coli = mt * 16 + q4 * 4 + r;
                        stgC[rowh * 68 + coli] = accC[mt][nt][r];
                        stgT[rowh * 68 + coli] = accT[mt][nt][r];
                    }
        }
        __syncthreads();
#pragma unroll 4
        for (int p = 0; p < 16; ++p) {
            int hl = hb + p * 4;
            int h = g * 64 + hl;
            float vc = stgC[hl * 68 + ii] * riv;
            float vt = stgT[hl * 68 + ii] * riv;
            size_t base = ((size_t)b * kH + h) * kC + i0 + ii;
            float c = ctx[base];
            out[base]         = c;
            out[N + base]     = vc;
            out[2 * N + base] = c * vc;
            out[3 * N + base] = c * vt;
        }
        __syncthreads();
    }
}

extern "C" void kernel_launch(void* const* d_in, const int* in_sizes, int n_in,
                              void* d_out, int out_size, void* d_ws, size_t ws_size,
                              hipStream_t stream) {
    const float* ctx   = (const float*)d_in[0];
    const float* q     = (const float*)d_in[1];
    const int*   cmask = (const int*)d_in[2];
    const int*   qmask = (const int*)d_in[3];
    const float* w_c   = (const float*)d_in[4];
    const float* w_q   = (const float*)d_in[5];
    const float* w_cq  = (const float*)d_in[6];
    const float* bias  = (const float*)d_in[7];
    float* out = (float*)d_out;

    // Workspace (~42 MB of 512 MiB).
    unsigned short* Eb = (unsigned short*)d_ws;                   // B*C*Q bf16
    unsigned short* qB = Eb + (size_t)kB * kC * kQ;               // B*H*Q bf16
    unsigned short* Tb = qB + (size_t)kB * kH * kQ;               // B*H*Q bf16
    float* part_q = (float*)(Tb + (size_t)kB * kH * kQ);          // B*Q
    float* rowinv = part_q + kB * kQ;                             // B*C
    float* colinv = rowinv + kB * kC;                             // B*Q
    float* ps     = colinv + kB * kQ;                             // B*128*Q
    size_t need = (size_t)((char*)(ps + (size_t)kB * kColChunks * kQ) - (char*)d_ws);
    if (ws_size < need) return;

    // d_out scratch (consumed before k_out_mfma writes):
    //   [0 ..)             : Tpart (8 * B*H*Q bf16 = 16.8 MB)
    //   [2N, ..) floats    : qT (B*Q*H bf16)
    const size_t N = (size_t)kB * kH * kC;
    unsigned short* Tpart = (unsigned short*)out;
    unsigned short* qT    = (unsigned short*)(out + 2 * N);

    k_prep_q<<<dim3(kQ / 64, kB), 256, 0, stream>>>(q, w_q, qT, qB, part_q);
    k_Ssoft<<<dim3(kC / 64, kB), 256, 0, stream>>>(ctx, qT, w_c, w_cq, part_q, bias,
                                                   qmask, cmask, Eb, rowinv, ps);
    k_colZ<<<kB * kQ / 256, 256, 0, stream>>>(ps, colinv);
    k_T2_mfma<<<dim3(8, kB), 512, 0, stream>>>(Eb, ctx, cmask, Tpart);
    k_Tred<<<kB * kH * kQ / 256, 256, 0, stream>>>(Tpart, colinv, Tb);
    k_out_mfma<<<dim3(kC / 64, kB), 256, 0, stream>>>(Eb, qB, Tb, ctx, rowinv, out);
}